// Round 5
// baseline (335.912 us; speedup 1.0000x reference)
//
#include <hip/hip_runtime.h>
#include <hip/hip_bf16.h>

// GCN decoder, 4 dispatches:
//  1) prep_t0_k: blocks 0-255 compute msg0 = lat@W0+b0; blocks 256+ transpose W1/W2/Wout.
//  2-4) agg_k<MODE,ADJW>: h = relu(adj@msg) + fused epilogue GEMM.
// Key round-5 change: K-chunk=256 with only A staged in LDS (8 barriers/block, was 64);
// B fragments read per-wave from L2-resident msgT (XCD swizzle batch=blockIdx&7).
// gfx950 __syncthreads drains vmcnt(0) -> barrier count is the latency multiplier.

typedef __bf16 bf16;
typedef __bf16 bf16x8 __attribute__((ext_vector_type(8)));
typedef float  f32x16 __attribute__((ext_vector_type(16)));
typedef float  f32x4  __attribute__((ext_vector_type(4)));

static __device__ inline f32x16 mfma32(bf16x8 a, bf16x8 b, f32x16 c) {
    return __builtin_amdgcn_mfma_f32_32x32x16_bf16(a, b, c, 0, 0, 0);
}

#define NB   8
#define NN   2048
#define LAT  64
#define HID  128
#define ODIM 64

// ---------------- dispatch 1: transform0 (blocks 0-255) + weight prep (blocks 256+) ----
__global__ __launch_bounds__(256) void prep_t0_k(
    const float* __restrict__ lat, const float* __restrict__ W0,
    const float* __restrict__ b0,
    const float* __restrict__ W1, const float* __restrict__ W2,
    const float* __restrict__ Wout,
    bf16* __restrict__ msgT, bf16* __restrict__ WT1,
    bf16* __restrict__ WT2, bf16* __restrict__ WoutT)
{
    __shared__ __align__(16) bf16 WTs[HID * 72];
    int tid = threadIdx.x;
    int blk = blockIdx.x;

    if (blk >= 256) {
        int i = (blk - 256) * 256 + tid;
        if (i < HID * HID) { int fo = i >> 7, k = i & 127; WT1[i] = (bf16)W1[k * HID + fo]; return; }
        i -= HID * HID;
        if (i < HID * HID) { int fo = i >> 7, k = i & 127; WT2[i] = (bf16)W2[k * HID + fo]; return; }
        i -= HID * HID;
        if (i < ODIM * HID) { int o = i >> 7, k = i & 127; WoutT[i] = (bf16)Wout[k * ODIM + o]; return; }
        return;
    }

    for (int i = tid; i < LAT * HID; i += 256) {
        int k = i >> 7, fo = i & 127;
        WTs[fo * 72 + k] = (bf16)W0[i];
    }
    __syncthreads();

    int l = tid & 63, w = tid >> 6;
    int lm = l & 31, lh = l >> 5;
    int g0 = blk * 64;
    int b  = g0 >> 11, nb = g0 & 2047;

    const bf16*  Wrow = &WTs[(w * 32 + lm) * 72 + lh * 8];
    const float* r0   = lat + (size_t)(g0 + lm) * LAT + lh * 8;
    const float* r1   = r0 + (size_t)32 * LAT;

    f32x16 acc0 = {}, acc1 = {};
#pragma unroll
    for (int k0 = 0; k0 < LAT; k0 += 16) {
        bf16x8 a = *(const bf16x8*)(Wrow + k0);
        f32x4 x0 = *(const f32x4*)(r0 + k0), x1 = *(const f32x4*)(r0 + k0 + 4);
        f32x4 y0 = *(const f32x4*)(r1 + k0), y1 = *(const f32x4*)(r1 + k0 + 4);
        bf16x8 v0, v1;
        v0[0]=(bf16)x0[0]; v0[1]=(bf16)x0[1]; v0[2]=(bf16)x0[2]; v0[3]=(bf16)x0[3];
        v0[4]=(bf16)x1[0]; v0[5]=(bf16)x1[1]; v0[6]=(bf16)x1[2]; v0[7]=(bf16)x1[3];
        v1[0]=(bf16)y0[0]; v1[1]=(bf16)y0[1]; v1[2]=(bf16)y0[2]; v1[3]=(bf16)y0[3];
        v1[4]=(bf16)y1[0]; v1[5]=(bf16)y1[1]; v1[6]=(bf16)y1[2]; v1[7]=(bf16)y1[3];
        acc0 = mfma32(a, v0, acc0);
        acc1 = mfma32(a, v1, acc1);
    }

    bf16* outb = msgT + (size_t)b * (HID * NN) + nb;
#pragma unroll
    for (int r = 0; r < 16; ++r) {
        int fo = w * 32 + (r & 3) + 8 * (r >> 2) + 4 * lh;
        float bv = b0[fo];
        outb[(size_t)fo * NN + lm]      = (bf16)(acc0[r] + bv);
        outb[(size_t)fo * NN + 32 + lm] = (bf16)(acc1[r] + bv);
    }
}

// ---------------- dispatches 2-4: fused aggregate ----------------
// Block: 32 nodes (m-tile) x 128 feats, 4 waves (one 32-feat col-tile each).
// K-chunk 256, A double-buffered in LDS (stride 264), 8 barriers/block.
template<int MODE, int ADJW>
__global__ __launch_bounds__(256, 3) void agg_k(
    const float* __restrict__ adjf, const bf16* __restrict__ adjbi,
    bf16* __restrict__ adjbo,
    const bf16* __restrict__ msgT, const bf16* __restrict__ WTn,
    const float* __restrict__ biasn, bf16* __restrict__ msg_out,
    const float* __restrict__ mask, float* __restrict__ out)
{
    constexpr int BKC = 256;        // K-chunk
    constexpr int SA  = 264;        // LDS row stride, elems (132 dw = 4 mod 32: conflict-free)
    __shared__ __align__(16) bf16 As[2][32 * SA];   // 2 x 16.5 KiB
    __shared__ __align__(16) bf16 Hs[32 * 136];     // 8.5 KiB

    int tid = threadIdx.x;
    int l = tid & 63, w = tid >> 6;
    int lm = l & 31, lh = l >> 5;
    int b  = blockIdx.x & 7;            // XCD swizzle: batch b -> XCD b (msg panel L2-hot)
    int m0 = (blockIdx.x >> 3) * 32;

    const bf16* msgb = msgT + (size_t)b * (HID * NN);
    // per-wave B fragment base: feat row w*32+lm, k offset lh*8 (scattered, L2-hot)
    const bf16* bsrc = msgb + (size_t)(w * 32 + lm) * NN + lh * 8;

    // A staging: row r = tid>>3 (32 rows), col base c0 = (tid&7)*32 within chunk
    // (per row: 8 threads x 32 elems -> dense 1 KiB fp32 / 512 B bf16)
    int r = tid >> 3, c0 = (tid & 7) * 32;
    const float* af  = (ADJW == 0) ? adjf  + (size_t)b * NN * NN + (size_t)(m0 + r) * NN + c0 : nullptr;
    bf16*        awb = (ADJW == 0) ? adjbo + (size_t)b * NN * NN + (size_t)(m0 + r) * NN + c0 : nullptr;
    const bf16*  ab  = (ADJW == 1) ? adjbi + (size_t)b * NN * NN + (size_t)(m0 + r) * NN + c0 : nullptr;

    f32x4  fa[8];
    bf16x8 ba[4];

    auto loadA = [&](int k0) {
        if (ADJW == 0) {
#pragma unroll
            for (int i = 0; i < 8; ++i) fa[i] = *(const f32x4*)(af + k0 + i * 4);
        } else {
#pragma unroll
            for (int i = 0; i < 4; ++i) ba[i] = *(const bf16x8*)(ab + k0 + i * 8);
        }
    };
    auto storeA = [&](int buf, int k0) {
        if (ADJW == 0) {
#pragma unroll
            for (int i = 0; i < 4; ++i) {
                bf16x8 v;
                v[0]=(bf16)fa[2*i][0];   v[1]=(bf16)fa[2*i][1];
                v[2]=(bf16)fa[2*i][2];   v[3]=(bf16)fa[2*i][3];
                v[4]=(bf16)fa[2*i+1][0]; v[5]=(bf16)fa[2*i+1][1];
                v[6]=(bf16)fa[2*i+1][2]; v[7]=(bf16)fa[2*i+1][3];
                *(bf16x8*)&As[buf][r * SA + c0 + i * 8] = v;
                *(bf16x8*)(awb + k0 + i * 8) = v;       // bf16 adj writeback for layers 2-3
            }
        } else {
#pragma unroll
            for (int i = 0; i < 4; ++i)
                *(bf16x8*)&As[buf][r * SA + c0 + i * 8] = ba[i];
        }
    };

    f32x16 acc = {};
    loadA(0);
    storeA(0, 0);
    __syncthreads();

    bf16x8 bb[16];
#pragma unroll 1
    for (int c = 0; c < 8; ++c) {
        int cur = c & 1;
        int k0 = c * BKC;
        // B fragments for this chunk (16 x 16B, per-wave, no barrier coupling)
#pragma unroll
        for (int s = 0; s < 16; ++s) bb[s] = *(const bf16x8*)(bsrc + k0 + s * 16);
        if (c < 7) loadA(k0 + BKC);
        const bf16* Ac = &As[cur][lm * SA + lh * 8];
#pragma unroll
        for (int s = 0; s < 16; ++s)
            acc = mfma32(*(const bf16x8*)(Ac + s * 16), bb[s], acc);
        if (c < 7) storeA(cur ^ 1, k0 + BKC);
        __syncthreads();
    }

    // relu(h) -> LDS [node][feat]
#pragma unroll
    for (int rr = 0; rr < 16; ++rr) {
        int row = (rr & 3) + 8 * (rr >> 2) + 4 * lh;
        float v = acc[rr];
        Hs[row * 136 + w * 32 + lm] = (bf16)(v > 0.f ? v : 0.f);
    }
    __syncthreads();

    if (MODE == 0) {
        // msg_out[fo][m0+node] = WTn[fo][:] . h[node][:] + biasn[fo]
        const bf16* Arow = WTn + (size_t)(w * 32 + lm) * HID + lh * 8;
        const bf16* Brow = &Hs[lm * 136 + lh * 8];
        f32x16 acc2 = {};
#pragma unroll
        for (int s = 0; s < 8; ++s)
            acc2 = mfma32(*(const bf16x8*)(Arow + s * 16), *(const bf16x8*)(Brow + s * 16), acc2);
        bf16* outb = msg_out + (size_t)b * (HID * NN) + m0;
#pragma unroll
        for (int rr = 0; rr < 16; ++rr) {
            int fo = w * 32 + (rr & 3) + 8 * (rr >> 2) + 4 * lh;
            outb[(size_t)fo * NN + lm] = (bf16)(acc2[rr] + biasn[fo]);
        }
    } else {
        if (w < 2) {
            int ob = w * 32;
            const bf16* Arow = &Hs[lm * 136 + lh * 8];
            const bf16* Brow = WTn + (size_t)(ob + lm) * HID + lh * 8;
            f32x16 acc2 = {};
#pragma unroll
            for (int s = 0; s < 8; ++s)
                acc2 = mfma32(*(const bf16x8*)(Arow + s * 16), *(const bf16x8*)(Brow + s * 16), acc2);
            float bv = biasn[ob + lm];
#pragma unroll
            for (int rr = 0; rr < 16; ++rr) {
                int node = (rr & 3) + 8 * (rr >> 2) + 4 * lh;
                int g = b * NN + m0 + node;
                out[(size_t)g * ODIM + ob + lm] = (acc2[rr] + bv) * mask[g];
            }
        }
    }
}

extern "C" void kernel_launch(void* const* d_in, const int* in_sizes, int n_in,
                              void* d_out, int out_size, void* d_ws, size_t ws_size,
                              hipStream_t stream)
{
    const float* lat  = (const float*)d_in[0];
    const float* adj  = (const float*)d_in[1];
    const float* mask = (const float*)d_in[2];
    const float* W0   = (const float*)d_in[3];
    const float* b0   = (const float*)d_in[4];
    const float* W1   = (const float*)d_in[5];
    const float* b1   = (const float*)d_in[6];
    const float* W2   = (const float*)d_in[7];
    const float* b2   = (const float*)d_in[8];
    const float* Wout = (const float*)d_in[9];
    const float* bout = (const float*)d_in[10];
    float* out = (float*)d_out;

    char* ws = (char*)d_ws;
    bf16* msgA  = (bf16*)(ws + 0);            // 4 MiB
    bf16* msgB  = (bf16*)(ws + 4194304);      // 4 MiB
    bf16* adjbf = (bf16*)(ws + 8388608);      // 64 MiB
    bf16* WT1   = (bf16*)(ws + 75497472);     // 32 KiB
    bf16* WT2   = (bf16*)(ws + 75530240);     // 32 KiB
    bf16* WoutT = (bf16*)(ws + 75563008);     // 16 KiB

    prep_t0_k<<<416, 256, 0, stream>>>(lat, W0, b0, W1, W2, Wout, msgA, WT1, WT2, WoutT);

    agg_k<0, 0><<<512, 256, 0, stream>>>(adj, nullptr, adjbf, msgA, WT1, b1, msgB, nullptr, nullptr);
    agg_k<0, 1><<<512, 256, 0, stream>>>(nullptr, adjbf, nullptr, msgB, WT2, b2, msgA, nullptr, nullptr);
    agg_k<1, 1><<<512, 256, 0, stream>>>(nullptr, adjbf, nullptr, msgA, WoutT, bout, nullptr, mask, out);
}